// Round 1
// baseline (27884.195 us; speedup 1.0000x reference)
//
#include <hip/hip_runtime.h>
#include <stddef.h>

#define T_STEPS 1024
#define NBLK 128   // 64 WGs for layer 0, 64 WGs for layer 1; <=256 CUs -> co-resident

typedef __attribute__((ext_vector_type(8))) short bf16x8;
typedef __attribute__((ext_vector_type(4))) float f32x4;

// ws layout (bytes)
#define OFF_XB   ((size_t)0)                    // bf16 x   [64][1024][1024]
#define OFF_W    ((size_t)134217728)            // bf16 wts [wih0,whh0,wih1,whh1] each [1024][1024]
#define OFF_H0   (OFF_W + (size_t)8388608)      // bf16 h0 slots [2][64][1024]
#define OFF_H1   (OFF_H0 + (size_t)262144)      // bf16 h1 slots [2][64][1024]
#define OFF_B    (OFF_H1 + (size_t)262144)      // f32 bias [2][1024] (bih+bhh combined)
#define OFF_CTR  (OFF_B + (size_t)8192)         // int barrier counter

__device__ __forceinline__ unsigned short f2bf(float f) {
  unsigned int u = __float_as_uint(f);
  u += 0x7fffu + ((u >> 16) & 1u);   // round-to-nearest-even
  return (unsigned short)(u >> 16);
}

__global__ void k_cvt_x(const float4* __restrict__ x4, ushort4* __restrict__ xb4) {
  size_t i = (size_t)blockIdx.x * blockDim.x + threadIdx.x;   // 16777216 float4s
  float4 v = x4[i];
  ushort4 o;
  o.x = f2bf(v.x); o.y = f2bf(v.y); o.z = f2bf(v.z); o.w = f2bf(v.w);
  xb4[i] = o;
}

__global__ void k_cvt_w(const float* __restrict__ Wih, const float* __restrict__ Whh,
                        ushort4* __restrict__ wt4) {
  size_t i4 = (size_t)blockIdx.x * blockDim.x + threadIdx.x;  // 1048576
  size_t e = i4 << 2;
  int arr = (int)(e >> 20);                  // 0:wih0 1:whh0 2:wih1 3:whh1
  size_t within = e & (size_t)1048575;
  const float* src = ((arr & 1) ? Whh : Wih) + ((arr >> 1) ? (size_t)1048576 : (size_t)0) + within;
  float4 v = *(const float4*)src;
  ushort4 o;
  o.x = f2bf(v.x); o.y = f2bf(v.y); o.z = f2bf(v.z); o.w = f2bf(v.w);
  wt4[i4] = o;
}

__global__ void k_init(const float* __restrict__ h0in, const float* __restrict__ bih,
                       const float* __restrict__ bhh,
                       unsigned short* __restrict__ h0s, unsigned short* __restrict__ h1s,
                       float* __restrict__ bias, int* __restrict__ ctr) {
  int tid = blockIdx.x * blockDim.x + threadIdx.x;  // 131072 = 64*2*1024
  int b = tid >> 11, rem = tid & 2047, l = rem >> 10, j = rem & 1023;
  float v = h0in[tid];                              // flat (b,l,j) == tid
  unsigned short* dst = l ? h1s : h0s;
  dst[(1 << 16) + (b << 10) + j] = f2bf(v);         // h_{-1} lives in slot 1
  if (tid < 2048) bias[tid] = bih[tid] + bhh[tid];
  if (tid == 0) *ctr = 0;
}

// Persistent pipelined RNN.
// Phase p: layer-0 WGs (g=0) compute h0_p = tanh(x_p@Wih0^T + h0_{p-1}@Whh0^T + b0)
//          layer-1 WGs (g=1) compute h1_{p-1} = tanh(h0_{p-1}@Wih1^T + h1_{p-2}@Whh1^T + b1)
// Both read only phase-(p-1) results -> one grid barrier per phase.
// Slots: h0_p -> p&1 ; h1_{p-1} -> (p+1)&1.
__global__ __launch_bounds__(128) void k_rnn(
    const unsigned short* __restrict__ xb,
    const unsigned short* __restrict__ wts,
    unsigned short* __restrict__ h0s,
    unsigned short* __restrict__ h1s,
    const float* __restrict__ bias,
    int* ctr,
    float* __restrict__ out)
{
  // 16 cols x K=2048 of bf16 weights, fragment-linear: chunk (kc=k/8, c) at 16B offset (kc*16+c)*16
  __shared__ __align__(16) unsigned short wlds[32768];   // exactly 64 KB

  const int wg = blockIdx.x;
  const int g = wg >> 6;                 // 0: layer0, 1: layer1
  const int cbase = (wg & 63) << 4;      // 16 output columns per WG
  const int tid = threadIdx.x;
  const int lane = tid & 63;
  const int wave = tid >> 6;             // 2 waves/WG; each wave: 2 row-tiles (32 rows)

  {  // preload weight slice into LDS (once)
    const unsigned short* wa = wts + ((size_t)(g * 2) << 20);       // K 0..1023
    const unsigned short* wb = wts + ((size_t)(g * 2 + 1) << 20);   // K 1024..2047
    for (int i = 0; i < 32; ++i) {
      int chunk = i * 128 + tid;         // 4096 chunks of 16B
      int kc = chunk >> 4, c = chunk & 15;
      int k = kc << 3;
      const unsigned short* s = (k < 1024)
          ? (wa + (((size_t)(cbase + c)) << 10) + k)
          : (wb + (((size_t)(cbase + c)) << 10) + (k - 1024));
      *(int4*)(&wlds[(size_t)chunk * 8]) = *(const int4*)s;
    }
  }
  __syncthreads();

  const int am = lane & 15;              // A row within tile / C col
  const int akk = (lane >> 4) << 3;      // A k-offset within 32-chunk
  const int arow0 = (wave << 5) + am;    // tile0 A row; tile1 = +16
  const float biasv = bias[(g << 10) + cbase + am];
  const int ccol = cbase + am;
  const int crow0 = (wave << 5) + ((lane >> 4) << 2);

  float* __restrict__ hfin = out + (size_t)67108864;

  for (int p = 0; p <= T_STEPS; ++p) {
    f32x4 acc0 = {0.f, 0.f, 0.f, 0.f};
    f32x4 acc1 = {0.f, 0.f, 0.f, 0.f};
    const bool active = (g == 0) ? (p < T_STEPS) : (p >= 1);
    const int t = (g == 0) ? p : (p - 1);

    // x-projection: no cross-phase dependency -> runs BEFORE the barrier wait
    if (g == 0 && active) {
      const unsigned short* a0p = xb + (((size_t)arow0 * T_STEPS + t) << 10) + akk;
      const unsigned short* a1p = xb + (((size_t)(arow0 + 16) * T_STEPS + t) << 10) + akk;
      #pragma unroll 8
      for (int k0 = 0; k0 < 1024; k0 += 32) {
        bf16x8 b  = *(const bf16x8*)(&wlds[k0 * 16 + lane * 8]);
        bf16x8 a0 = *(const bf16x8*)(a0p + k0);
        bf16x8 a1 = *(const bf16x8*)(a1p + k0);
        acc0 = __builtin_amdgcn_mfma_f32_16x16x32_bf16(a0, b, acc0, 0, 0, 0);
        acc1 = __builtin_amdgcn_mfma_f32_16x16x32_bf16(a1, b, acc1, 0, 0, 0);
      }
    }

    if (p > 0) {
      if (tid == 0) {
        const int target = NBLK * p;
        while (__hip_atomic_load(ctr, __ATOMIC_RELAXED, __HIP_MEMORY_SCOPE_AGENT) < target)
          __builtin_amdgcn_s_sleep(2);
      }
      __syncthreads();
      __threadfence();   // acquire: invalidate stale L1/L2 lines of h slots (cross-XCD)
    }

    if (active) {
      if (g == 1) {  // layer1 first half: h0_{p-1} @ Wih1^T
        const unsigned short* hsrc = h0s + (((size_t)(t & 1)) << 16);
        const unsigned short* a0p = hsrc + (((size_t)arow0) << 10) + akk;
        #pragma unroll 8
        for (int k0 = 0; k0 < 1024; k0 += 32) {
          bf16x8 b  = *(const bf16x8*)(&wlds[k0 * 16 + lane * 8]);
          bf16x8 a0 = *(const bf16x8*)(a0p + k0);
          bf16x8 a1 = *(const bf16x8*)(a0p + (16 << 10) + k0);
          acc0 = __builtin_amdgcn_mfma_f32_16x16x32_bf16(a0, b, acc0, 0, 0, 0);
          acc1 = __builtin_amdgcn_mfma_f32_16x16x32_bf16(a1, b, acc1, 0, 0, 0);
        }
      }
      {  // recurrent half: h_{prev} @ Whh^T  (K 1024..2047 in LDS)
        const unsigned short* hsrc = (g == 0)
            ? (h0s + (((size_t)((p + 1) & 1)) << 16))    // h0_{p-1}
            : (h1s + (((size_t)(p & 1)) << 16));         // h1_{p-2}
        const unsigned short* a0p = hsrc + (((size_t)arow0) << 10) + akk;
        #pragma unroll 8
        for (int k0 = 0; k0 < 1024; k0 += 32) {
          bf16x8 b  = *(const bf16x8*)(&wlds[(k0 + 1024) * 16 + lane * 8]);
          bf16x8 a0 = *(const bf16x8*)(a0p + k0);
          bf16x8 a1 = *(const bf16x8*)(a0p + (16 << 10) + k0);
          acc0 = __builtin_amdgcn_mfma_f32_16x16x32_bf16(a0, b, acc0, 0, 0, 0);
          acc1 = __builtin_amdgcn_mfma_f32_16x16x32_bf16(a1, b, acc1, 0, 0, 0);
        }
      }

      unsigned short* hdst = (g == 0)
          ? (h0s + (((size_t)(p & 1)) << 16))
          : (h1s + (((size_t)((p + 1) & 1)) << 16));
      #pragma unroll
      for (int i = 0; i < 4; ++i) {
        {
          const int brow = crow0 + i;
          const float v = tanhf(acc0[i] + biasv);
          hdst[((size_t)brow << 10) + ccol] = f2bf(v);
          if (g == 1) out[((((size_t)t << 6) + brow) << 10) + ccol] = v;   // y[t][b][c]
          if (t == T_STEPS - 1) hfin[((size_t)(brow * 2 + g) << 10) + ccol] = v;
        }
        {
          const int brow = crow0 + 16 + i;
          const float v = tanhf(acc1[i] + biasv);
          hdst[((size_t)brow << 10) + ccol] = f2bf(v);
          if (g == 1) out[((((size_t)t << 6) + brow) << 10) + ccol] = v;
          if (t == T_STEPS - 1) hfin[((size_t)(brow * 2 + g) << 10) + ccol] = v;
        }
      }
    }

    __threadfence();      // release: drain own stores + write back XCD L2
    __syncthreads();      // all waves of this WG drained before arrival
    if (tid == 0) __hip_atomic_fetch_add(ctr, 1, __ATOMIC_RELEASE, __HIP_MEMORY_SCOPE_AGENT);
  }
}

extern "C" void kernel_launch(void* const* d_in, const int* in_sizes, int n_in,
                              void* d_out, int out_size, void* d_ws, size_t ws_size,
                              hipStream_t stream) {
  (void)in_sizes; (void)n_in; (void)out_size; (void)ws_size;
  const float* x   = (const float*)d_in[0];
  const float* h0  = (const float*)d_in[1];
  const float* Wih = (const float*)d_in[2];
  const float* bih = (const float*)d_in[3];
  const float* Whh = (const float*)d_in[4];
  const float* bhh = (const float*)d_in[5];
  float* out = (float*)d_out;
  char* ws = (char*)d_ws;

  unsigned short* xb  = (unsigned short*)(ws + OFF_XB);
  unsigned short* wts = (unsigned short*)(ws + OFF_W);
  unsigned short* h0s = (unsigned short*)(ws + OFF_H0);
  unsigned short* h1s = (unsigned short*)(ws + OFF_H1);
  float* bias = (float*)(ws + OFF_B);
  int* ctr = (int*)(ws + OFF_CTR);

  k_cvt_x<<<65536, 256, 0, stream>>>((const float4*)x, (ushort4*)xb);
  k_cvt_w<<<4096, 256, 0, stream>>>(Wih, Whh, (ushort4*)wts);
  k_init<<<512, 256, 0, stream>>>(h0, bih, bhh, h0s, h1s, bias, ctr);
  k_rnn<<<NBLK, 128, 0, stream>>>(xb, wts, h0s, h1s, bias, ctr, out);
}